// Round 1
// baseline (18551.892 us; speedup 1.0000x reference)
//
#include <hip/hip_runtime.h>
#include <hip/hip_fp16.h>

typedef float  f4v __attribute__((ext_vector_type(4)));
typedef _Float16 h8v __attribute__((ext_vector_type(8)));
typedef _Float16 h4v __attribute__((ext_vector_type(4)));

#define B_ 64
#define T_ 512
#define H_ 1024

// ---------------------------------------------------------------------------
// Transpose 1024x1024 f32 -> f16 (dst[j][i] = src[i][j]).  Used for U and W so
// MFMA B-fragments can be loaded as contiguous k-runs (ds_read_b128).
// ---------------------------------------------------------------------------
__global__ __launch_bounds__(256) void k_transpose_cvt(const float* __restrict__ src,
                                                       _Float16* __restrict__ dst) {
  __shared__ _Float16 tile[64][72];  // 144B row stride, 16B aligned
  int r0 = blockIdx.y * 64, c0 = blockIdx.x * 64;
  int t = threadIdx.x;
  for (int i = 0; i < 4; ++i) {
    int r = i * 16 + (t >> 4);
    int c = (t & 15) * 4;
    f4v v = *reinterpret_cast<const f4v*>(src + (long)(r0 + r) * 1024 + c0 + c);
    tile[c + 0][r] = (_Float16)v.x;
    tile[c + 1][r] = (_Float16)v.y;
    tile[c + 2][r] = (_Float16)v.z;
    tile[c + 3][r] = (_Float16)v.w;
  }
  __syncthreads();
  for (int i = 0; i < 2; ++i) {
    int rr = i * 32 + (t >> 3);
    int cc = (t & 7) * 8;
    *reinterpret_cast<h8v*>(dst + (long)(c0 + rr) * 1024 + r0 + cc) =
        *reinterpret_cast<const h8v*>(&tile[rr][cc]);
  }
}

// ---------------------------------------------------------------------------
// xU GEMM: out[b*T+t][h] = x[b*T+t][:] @ U[:][h] + bias[h]   (f32 out)
// M=32768, N=1024, K=1024.  BM=BN=128, BK=32, 256 thr (4 waves, each 64x64).
// Reg-staged with on-the-fly f32->f16 conversion (A) / f16 copy (B=Ut rows).
// ---------------------------------------------------------------------------
#define SWZG(r, kh) ((((r) * 64) + ((kh) * 2)) ^ (((r) & 3) << 4))

__global__ __launch_bounds__(256) void k_gemm_xu(const float* __restrict__ x,
                                                 const _Float16* __restrict__ Ut,
                                                 const float* __restrict__ bias,
                                                 float* __restrict__ out) {
  __shared__ __attribute__((aligned(16))) unsigned char Asm[128 * 32 * 2];
  __shared__ __attribute__((aligned(16))) unsigned char Bsm[128 * 32 * 2];
  int bid = blockIdx.x;
  int nt = bid & 7, mt = bid >> 3;  // n-fastest: concurrent blocks share x rows in LLC
  int t = threadIdx.x;
  int row = t >> 1, kc = (t & 1) * 16;
  long gA = (long)(mt * 128 + row) * 1024 + kc;
  long gB = (long)(nt * 128 + row) * 1024 + kc;
  int wid = t >> 6, lane = t & 63;
  int wr = (wid >> 1) * 64, wc = (wid & 1) * 64;
  int l15 = lane & 15, khi = (lane >> 4) * 8;

  f4v acc[4][4];
  for (int i = 0; i < 4; ++i)
    for (int j = 0; j < 4; ++j) acc[i][j] = (f4v){0.f, 0.f, 0.f, 0.f};

  f4v ra[4];
  h8v rb[2];
  {
    const float* ap = x + gA;
    ra[0] = *(const f4v*)(ap);     ra[1] = *(const f4v*)(ap + 4);
    ra[2] = *(const f4v*)(ap + 8); ra[3] = *(const f4v*)(ap + 12);
    const _Float16* bp = Ut + gB;
    rb[0] = *(const h8v*)(bp);     rb[1] = *(const h8v*)(bp + 8);
  }
  for (int kt = 0; kt < 32; ++kt) {
    h8v ah0, ah1;
    for (int j = 0; j < 4; ++j) {
      ah0[j]     = (_Float16)ra[0][j];
      ah0[j + 4] = (_Float16)ra[1][j];
      ah1[j]     = (_Float16)ra[2][j];
      ah1[j + 4] = (_Float16)ra[3][j];
    }
    *(h8v*)(Asm + SWZG(row, kc))     = ah0;
    *(h8v*)(Asm + SWZG(row, kc + 8)) = ah1;
    *(h8v*)(Bsm + SWZG(row, kc))     = rb[0];
    *(h8v*)(Bsm + SWZG(row, kc + 8)) = rb[1];
    __syncthreads();
    if (kt < 31) {  // prefetch next K-tile while MFMAs run
      const float* ap = x + gA + (kt + 1) * 32;
      ra[0] = *(const f4v*)(ap);     ra[1] = *(const f4v*)(ap + 4);
      ra[2] = *(const f4v*)(ap + 8); ra[3] = *(const f4v*)(ap + 12);
      const _Float16* bp = Ut + gB + (kt + 1) * 32;
      rb[0] = *(const h8v*)(bp);     rb[1] = *(const h8v*)(bp + 8);
    }
    h8v af[4], bf[4];
    for (int mi = 0; mi < 4; ++mi)
      af[mi] = *(const h8v*)(Asm + SWZG(wr + mi * 16 + l15, khi));
    for (int ni = 0; ni < 4; ++ni)
      bf[ni] = *(const h8v*)(Bsm + SWZG(wc + ni * 16 + l15, khi));
    for (int mi = 0; mi < 4; ++mi)
      for (int ni = 0; ni < 4; ++ni)
        acc[mi][ni] = __builtin_amdgcn_mfma_f32_16x16x32_f16(af[mi], bf[ni], acc[mi][ni], 0, 0, 0);
    __syncthreads();
  }
  int coff = nt * 128 + wc, roff = mt * 128 + wr;
  for (int ni = 0; ni < 4; ++ni) {
    int col = coff + ni * 16 + l15;
    float bb = bias[col];
    for (int mi = 0; mi < 4; ++mi) {
      int rbase = roff + mi * 16 + (lane >> 4) * 4;
      for (int j = 0; j < 4; ++j)
        out[(long)(rbase + j) * 1024 + col] = acc[mi][ni][j] + bb;
    }
  }
}

// ---------------------------------------------------------------------------
// Persistent scan kernel (cooperative).  256 wgs = 8 clusters x 32 members.
// Cluster c owns batches [8c, 8c+8); member m owns output cols [32m, 32m+32),
// whose W columns (as Wt rows) live in LDS for the whole kernel.
// Per step: stage h(8x1024 f32->f16 LDS) -> 2 waves MFMA (16x16x32, K=1024)
// -> tanh(acc + xu) written in place into d_out -> agent-scope cluster barrier.
// d_out holds xU before step t overwrites row t with h_t (in-place).
// ---------------------------------------------------------------------------
#define SWZS(r, kh) ((((r) * 2048) + ((kh) * 2)) ^ (((r) & 7) << 4))

__global__ __launch_bounds__(256) void k_scan(const float* __restrict__ state,
                                              float* __restrict__ out,
                                              const _Float16* __restrict__ Wt,
                                              unsigned int* __restrict__ ctr) {
  extern __shared__ __attribute__((aligned(16))) unsigned char smem[];
  unsigned char* Wl = smem;          // 32 x 1024 f16, 2048B stride, swizzled (64 KB)
  unsigned char* Hl = smem + 65536;  // 8 x 1024 f16 (16 KB)
  int t = threadIdx.x;
  int cl = blockIdx.x & 7;   // cluster (also likely XCD under round-robin; not required)
  int mm = blockIdx.x >> 3;  // member 0..31

  {  // stage this member's 32 Wt rows into LDS (once)
    int r = t >> 3, c8 = t & 7;
    const _Float16* wsrc = Wt + (long)(mm * 32 + r) * 1024;
    for (int j = 0; j < 16; ++j) {
      int kh = (c8 + 8 * j) * 8;
      *(h8v*)(Wl + SWZS(r, kh)) = *(const h8v*)(wsrc + kh);
    }
  }

  unsigned int* myctr = ctr + cl * 64;  // 256B apart per cluster
  int wid = t >> 6, lane = t & 63;
  int srow = t >> 5, slane = t & 31;  // h staging: 8 rows x 32 threads
  long b = cl * 8 + srow;
  int l15 = lane & 15, khi8 = (lane >> 4) * 8;
  int arow = lane & 7;        // A rows 8..15 duplicate 0..7 (C rows 8..15 unused)
  int bro = wid * 16 + l15;   // local W row (= local out col)

  for (int step = 0; step < T_; ++step) {
    const float* hsrc = (step == 0) ? (state + b * 1024)
                                    : (out + (b * T_ + (step - 1)) * 1024);
    for (int j = 0; j < 8; ++j) {
      int k = (slane + 32 * j) * 4;
      f4v v = *(const f4v*)(hsrc + k);
      h4v hv;
      hv[0] = (_Float16)v.x; hv[1] = (_Float16)v.y;
      hv[2] = (_Float16)v.z; hv[3] = (_Float16)v.w;
      *(h4v*)(Hl + SWZS(srow, k)) = hv;
    }
    __syncthreads();  // (also covers initial W staging at step 0)

    if (wid < 2) {
      f4v acc = (f4v){0.f, 0.f, 0.f, 0.f};
      for (int s = 0; s < 32; ++s) {
        int k = s * 32 + khi8;
        h8v af = *(const h8v*)(Hl + SWZS(arow, k));
        h8v bf = *(const h8v*)(Wl + SWZS(bro, k));
        acc = __builtin_amdgcn_mfma_f32_16x16x32_f16(af, bf, acc, 0, 0, 0);
      }
      int hi = lane >> 4;
      if (hi < 2) {  // valid C rows 0..7 only
        int gcol = mm * 32 + wid * 16 + l15;
        for (int j = 0; j < 4; ++j) {
          long r = (long)cl * 8 + hi * 4 + j;
          long addr = (r * T_ + step) * 1024 + gcol;
          float v = tanhf(acc[j] + out[addr]);  // xu precomputed in d_out
          out[addr] = v;
          if (step == T_ - 1) out[(long)B_ * T_ * 1024 + r * 1024 + gcol] = v;
        }
      }
    }

    // release: flush stores to agent scope, then arrive+spin on cluster counter
    __threadfence();
    __syncthreads();
    if (t == 0) {
      __hip_atomic_fetch_add(myctr, 1u, __ATOMIC_RELEASE, __HIP_MEMORY_SCOPE_AGENT);
      unsigned int tgt = 32u * (unsigned)(step + 1);
      while (__hip_atomic_load(myctr, __ATOMIC_RELAXED, __HIP_MEMORY_SCOPE_AGENT) < tgt)
        __builtin_amdgcn_s_sleep(1);
    }
    __syncthreads();
    __threadfence();  // acquire: invalidate stale L2 before reading peers' h
  }
}

extern "C" void kernel_launch(void* const* d_in, const int* in_sizes, int n_in,
                              void* d_out, int out_size, void* d_ws, size_t ws_size,
                              hipStream_t stream) {
  const float* x     = (const float*)d_in[0];
  const float* state = (const float*)d_in[1];
  const float* W     = (const float*)d_in[2];
  const float* U     = (const float*)d_in[3];
  const float* bias  = (const float*)d_in[4];
  float* out = (float*)d_out;
  unsigned char* ws = (unsigned char*)d_ws;

  _Float16* Ut = (_Float16*)ws;                    // 2 MB
  _Float16* Wt = (_Float16*)(ws + (1u << 21));     // 2 MB
  unsigned int* ctr = (unsigned int*)(ws + (1u << 22));  // 2 KB barrier counters

  hipMemsetAsync(ctr, 0, 8 * 64 * sizeof(unsigned int), stream);

  k_transpose_cvt<<<dim3(16, 16), 256, 0, stream>>>(U, Ut);
  k_transpose_cvt<<<dim3(16, 16), 256, 0, stream>>>(W, Wt);
  k_gemm_xu<<<2048, 256, 0, stream>>>(x, Ut, bias, out);

  hipFuncSetAttribute((const void*)k_scan, hipFuncAttributeMaxDynamicSharedMemorySize, 81920);
  void* args[] = {(void*)&state, (void*)&out, (void*)&Wt, (void*)&ctr};
  hipLaunchCooperativeKernel((void*)k_scan, dim3(256), dim3(256), args, 81920, stream);
}

// Round 2
// 1602.405 us; speedup vs baseline: 11.5775x; 11.5775x over previous
//
#include <hip/hip_runtime.h>
#include <hip/hip_fp16.h>

typedef float  f4v __attribute__((ext_vector_type(4)));
typedef _Float16 h8v __attribute__((ext_vector_type(8)));
typedef _Float16 h4v __attribute__((ext_vector_type(4)));

#define B_ 64
#define T_ 512
#define H_ 1024

// ---------------------------------------------------------------------------
// Transpose 1024x1024 f32 -> f16 (dst[j][i] = src[i][j]).
// ---------------------------------------------------------------------------
__global__ __launch_bounds__(256) void k_transpose_cvt(const float* __restrict__ src,
                                                       _Float16* __restrict__ dst) {
  __shared__ _Float16 tile[64][72];
  int r0 = blockIdx.y * 64, c0 = blockIdx.x * 64;
  int t = threadIdx.x;
  for (int i = 0; i < 4; ++i) {
    int r = i * 16 + (t >> 4);
    int c = (t & 15) * 4;
    f4v v = *reinterpret_cast<const f4v*>(src + (long)(r0 + r) * 1024 + c0 + c);
    tile[c + 0][r] = (_Float16)v.x;
    tile[c + 1][r] = (_Float16)v.y;
    tile[c + 2][r] = (_Float16)v.z;
    tile[c + 3][r] = (_Float16)v.w;
  }
  __syncthreads();
  for (int i = 0; i < 2; ++i) {
    int rr = i * 32 + (t >> 3);
    int cc = (t & 7) * 8;
    *reinterpret_cast<h8v*>(dst + (long)(c0 + rr) * 1024 + r0 + cc) =
        *reinterpret_cast<const h8v*>(&tile[rr][cc]);
  }
}

// ---------------------------------------------------------------------------
// xU GEMM (unchanged from R1): out[m][n] = x[m][:] @ U[:][n] + bias[n]
// ---------------------------------------------------------------------------
#define SWZG(r, kh) ((((r) * 64) + ((kh) * 2)) ^ (((r) & 3) << 4))

__global__ __launch_bounds__(256) void k_gemm_xu(const float* __restrict__ x,
                                                 const _Float16* __restrict__ Ut,
                                                 const float* __restrict__ bias,
                                                 float* __restrict__ out) {
  __shared__ __attribute__((aligned(16))) unsigned char Asm[128 * 32 * 2];
  __shared__ __attribute__((aligned(16))) unsigned char Bsm[128 * 32 * 2];
  int bid = blockIdx.x;
  int nt = bid & 7, mt = bid >> 3;
  int t = threadIdx.x;
  int row = t >> 1, kc = (t & 1) * 16;
  long gA = (long)(mt * 128 + row) * 1024 + kc;
  long gB = (long)(nt * 128 + row) * 1024 + kc;
  int wid = t >> 6, lane = t & 63;
  int wr = (wid >> 1) * 64, wc = (wid & 1) * 64;
  int l15 = lane & 15, khi = (lane >> 4) * 8;

  f4v acc[4][4];
  for (int i = 0; i < 4; ++i)
    for (int j = 0; j < 4; ++j) acc[i][j] = (f4v){0.f, 0.f, 0.f, 0.f};

  f4v ra[4];
  h8v rb[2];
  {
    const float* ap = x + gA;
    ra[0] = *(const f4v*)(ap);     ra[1] = *(const f4v*)(ap + 4);
    ra[2] = *(const f4v*)(ap + 8); ra[3] = *(const f4v*)(ap + 12);
    const _Float16* bp = Ut + gB;
    rb[0] = *(const h8v*)(bp);     rb[1] = *(const h8v*)(bp + 8);
  }
  for (int kt = 0; kt < 32; ++kt) {
    h8v ah0, ah1;
    for (int j = 0; j < 4; ++j) {
      ah0[j]     = (_Float16)ra[0][j];
      ah0[j + 4] = (_Float16)ra[1][j];
      ah1[j]     = (_Float16)ra[2][j];
      ah1[j + 4] = (_Float16)ra[3][j];
    }
    *(h8v*)(Asm + SWZG(row, kc))     = ah0;
    *(h8v*)(Asm + SWZG(row, kc + 8)) = ah1;
    *(h8v*)(Bsm + SWZG(row, kc))     = rb[0];
    *(h8v*)(Bsm + SWZG(row, kc + 8)) = rb[1];
    __syncthreads();
    if (kt < 31) {
      const float* ap = x + gA + (kt + 1) * 32;
      ra[0] = *(const f4v*)(ap);     ra[1] = *(const f4v*)(ap + 4);
      ra[2] = *(const f4v*)(ap + 8); ra[3] = *(const f4v*)(ap + 12);
      const _Float16* bp = Ut + gB + (kt + 1) * 32;
      rb[0] = *(const h8v*)(bp);     rb[1] = *(const h8v*)(bp + 8);
    }
    h8v af[4], bf[4];
    for (int mi = 0; mi < 4; ++mi)
      af[mi] = *(const h8v*)(Asm + SWZG(wr + mi * 16 + l15, khi));
    for (int ni = 0; ni < 4; ++ni)
      bf[ni] = *(const h8v*)(Bsm + SWZG(wc + ni * 16 + l15, khi));
    for (int mi = 0; mi < 4; ++mi)
      for (int ni = 0; ni < 4; ++ni)
        acc[mi][ni] = __builtin_amdgcn_mfma_f32_16x16x32_f16(af[mi], bf[ni], acc[mi][ni], 0, 0, 0);
    __syncthreads();
  }
  int coff = nt * 128 + wc, roff = mt * 128 + wr;
  for (int ni = 0; ni < 4; ++ni) {
    int col = coff + ni * 16 + l15;
    float bb = bias[col];
    for (int mi = 0; mi < 4; ++mi) {
      int rbase = roff + mi * 16 + (lane >> 4) * 4;
      for (int j = 0; j < 4; ++j)
        out[(long)(rbase + j) * 1024 + col] = acc[mi][ni][j] + bb;
    }
  }
}

// ---------------------------------------------------------------------------
// Persistent scan kernel v2.  Same decomposition as R1 (8 clusters x 32
// members; member owns 32 cols, W block LDS-resident).  All cross-wg data
// moves via per-access agent-coherent (sc0 sc1) loads/stores -> NO cache-wide
// buffer_wbl2/buffer_inv in the loop.  Barrier = relaxed LLC atomic counter.
// ---------------------------------------------------------------------------
#define SWZS(r, kh) ((((r) * 2048) + ((kh) * 2)) ^ (((r) & 7) << 4))

__global__ __launch_bounds__(256) void k_scan(const float* __restrict__ state,
                                              float* __restrict__ out,
                                              const _Float16* __restrict__ Wt,
                                              unsigned int* __restrict__ ctr) {
  extern __shared__ __attribute__((aligned(16))) unsigned char smem[];
  unsigned char* Wl = smem;          // 32 x 1024 f16, swizzled (64 KB)
  unsigned char* Hl = smem + 65536;  // 8 x 1024 f16 (16 KB)
  int t = threadIdx.x;
  int cl = blockIdx.x & 7;
  int mm = blockIdx.x >> 3;

  {  // stage this member's 32 Wt rows into LDS (once)
    int r = t >> 3, c8 = t & 7;
    const _Float16* wsrc = Wt + (long)(mm * 32 + r) * 1024;
    for (int j = 0; j < 16; ++j) {
      int kh = (c8 + 8 * j) * 8;
      *(h8v*)(Wl + SWZS(r, kh)) = *(const h8v*)(wsrc + kh);
    }
  }

  unsigned int* myctr = ctr + cl * 64;
  int wid = t >> 6, lane = t & 63;
  int srow = t >> 5, slane = t & 31;
  long b = cl * 8 + srow;
  int l15 = lane & 15, khi8 = (lane >> 4) * 8;
  int arow = lane & 7;
  int bro = wid * 16 + l15;
  int hi = lane >> 4;
  int gcol = mm * 32 + wid * 16 + l15;

  for (int step = 0; step < T_; ++step) {
    const float* hsrc = (step == 0) ? (state + b * 1024)
                                    : (out + (b * T_ + (step - 1)) * 1024);
    // --- load h row (LLC-coherent, bypass L2), 8 x 16B, imm-offset strided ---
    const float* hp = hsrc + slane * 4;
    f4v w0, w1, w2, w3, w4, w5, w6, w7;
    asm volatile(
        "global_load_dwordx4 %0, %8, off sc0 sc1\n\t"
        "global_load_dwordx4 %1, %8, off offset:512 sc0 sc1\n\t"
        "global_load_dwordx4 %2, %8, off offset:1024 sc0 sc1\n\t"
        "global_load_dwordx4 %3, %8, off offset:1536 sc0 sc1\n\t"
        "global_load_dwordx4 %4, %8, off offset:2048 sc0 sc1\n\t"
        "global_load_dwordx4 %5, %8, off offset:2560 sc0 sc1\n\t"
        "global_load_dwordx4 %6, %8, off offset:3072 sc0 sc1\n\t"
        "global_load_dwordx4 %7, %8, off offset:3584 sc0 sc1\n\t"
        "s_waitcnt vmcnt(0)"
        : "=&v"(w0), "=&v"(w1), "=&v"(w2), "=&v"(w3),
          "=&v"(w4), "=&v"(w5), "=&v"(w6), "=&v"(w7)
        : "v"(hp)
        : "memory");
    // --- cvt f32->f16, stage into LDS ---
    {
      f4v wv[8] = {w0, w1, w2, w3, w4, w5, w6, w7};
#pragma unroll
      for (int j = 0; j < 8; ++j) {
        int k = (slane + 32 * j) * 4;
        h4v hv;
        hv[0] = (_Float16)wv[j][0]; hv[1] = (_Float16)wv[j][1];
        hv[2] = (_Float16)wv[j][2]; hv[3] = (_Float16)wv[j][3];
        *(h4v*)(Hl + SWZS(srow, k)) = hv;
      }
    }
    __syncthreads();  // also covers initial W staging at step 0

    if (wid < 2) {
      // xu loads early (own lines, never stale) to overlap with MFMA chain
      float xuv[4];
      long addr0 = 0;
      if (hi < 2) {
        addr0 = ((long)(cl * 8 + hi * 4) * T_ + step) * 1024 + gcol;
#pragma unroll
        for (int j = 0; j < 4; ++j) xuv[j] = out[addr0 + (long)j * T_ * 1024];
      }
      // K=1024 MFMA chain, 2 independent accumulators
      f4v acc0 = (f4v){0.f, 0.f, 0.f, 0.f}, acc1 = acc0;
#pragma unroll
      for (int s = 0; s < 32; s += 2) {
        int k0 = s * 32 + khi8, k1 = (s + 1) * 32 + khi8;
        h8v af0 = *(const h8v*)(Hl + SWZS(arow, k0));
        h8v bf0 = *(const h8v*)(Wl + SWZS(bro, k0));
        h8v af1 = *(const h8v*)(Hl + SWZS(arow, k1));
        h8v bf1 = *(const h8v*)(Wl + SWZS(bro, k1));
        acc0 = __builtin_amdgcn_mfma_f32_16x16x32_f16(af0, bf0, acc0, 0, 0, 0);
        acc1 = __builtin_amdgcn_mfma_f32_16x16x32_f16(af1, bf1, acc1, 0, 0, 0);
      }
      f4v acc = acc0 + acc1;
      if (hi < 2) {
        float v0 = tanhf(acc[0] + xuv[0]);
        float v1 = tanhf(acc[1] + xuv[1]);
        float v2 = tanhf(acc[2] + xuv[2]);
        float v3 = tanhf(acc[3] + xuv[3]);
        float* p0 = out + addr0;
        float* p1 = p0 + (long)T_ * 1024;
        float* p2 = p1 + (long)T_ * 1024;
        float* p3 = p2 + (long)T_ * 1024;
        // write-through to LLC + wait for ack (release payload for the barrier)
        asm volatile(
            "global_store_dword %0, %4, off sc0 sc1\n\t"
            "global_store_dword %1, %5, off sc0 sc1\n\t"
            "global_store_dword %2, %6, off sc0 sc1\n\t"
            "global_store_dword %3, %7, off sc0 sc1\n\t"
            "s_waitcnt vmcnt(0)"
            :: "v"(p0), "v"(p1), "v"(p2), "v"(p3),
               "v"(v0), "v"(v1), "v"(v2), "v"(v3)
            : "memory");
        if (step == T_ - 1) {
          long r = (long)cl * 8 + hi * 4;
          float* q = out + (long)B_ * T_ * 1024 + r * 1024 + gcol;
          q[0] = v0; q[1024] = v1; q[2048] = v2; q[3072] = v3;
        }
      }
    }

    // --- cluster barrier: relaxed LLC atomics only, no cache maintenance ---
    __syncthreads();  // all stores in wg complete (vmcnt(0) inside store asm)
    if (t == 0) {
      __hip_atomic_fetch_add(myctr, 1u, __ATOMIC_RELAXED, __HIP_MEMORY_SCOPE_AGENT);
      unsigned int tgt = 32u * (unsigned)(step + 1);
      while (__hip_atomic_load(myctr, __ATOMIC_RELAXED, __HIP_MEMORY_SCOPE_AGENT) < tgt)
        __builtin_amdgcn_s_sleep(1);
    }
    __syncthreads();
  }
}

extern "C" void kernel_launch(void* const* d_in, const int* in_sizes, int n_in,
                              void* d_out, int out_size, void* d_ws, size_t ws_size,
                              hipStream_t stream) {
  const float* x     = (const float*)d_in[0];
  const float* state = (const float*)d_in[1];
  const float* W     = (const float*)d_in[2];
  const float* U     = (const float*)d_in[3];
  const float* bias  = (const float*)d_in[4];
  float* out = (float*)d_out;
  unsigned char* ws = (unsigned char*)d_ws;

  _Float16* Ut = (_Float16*)ws;
  _Float16* Wt = (_Float16*)(ws + (1u << 21));
  unsigned int* ctr = (unsigned int*)(ws + (1u << 22));

  hipMemsetAsync(ctr, 0, 8 * 64 * sizeof(unsigned int), stream);

  k_transpose_cvt<<<dim3(16, 16), 256, 0, stream>>>(U, Ut);
  k_transpose_cvt<<<dim3(16, 16), 256, 0, stream>>>(W, Wt);
  k_gemm_xu<<<2048, 256, 0, stream>>>(x, Ut, bias, out);

  hipFuncSetAttribute((const void*)k_scan, hipFuncAttributeMaxDynamicSharedMemorySize, 81920);
  void* args[] = {(void*)&state, (void*)&out, (void*)&Wt, (void*)&ctr};
  hipLaunchCooperativeKernel((void*)k_scan, dim3(256), dim3(256), args, 81920, stream);
}